// Round 6
// baseline (366.919 us; speedup 1.0000x reference)
//
#include <hip/hip_runtime.h>

// WeightedGIN 2-layer + L2-normalize. N=50000, E=800000, D=64.
// dst-CSR built per call (hist + 2-stage scan + reorder), then atomic-free
// 16-lane-per-node gather (float4 rows), quad-per-node MLP (j-split x4 + shfl reduce).

#define DIM 64
#define SB 256   // scan block size

// ---- Pass 1: histogram of dst ----
__global__ __launch_bounds__(256) void hist_k(const int* __restrict__ ei,
                                              int* __restrict__ cnt, int n_edges) {
    int e = blockIdx.x * blockDim.x + threadIdx.x;
    if (e < n_edges) atomicAdd(&cnt[ei[n_edges + e]], 1);
}

// ---- Scan stage 1: per-block sums of cnt ----
__global__ __launch_bounds__(SB) void scan1_k(const int* __restrict__ cnt,
                                              int* __restrict__ bsum, int n) {
    __shared__ int red[SB];
    int i = blockIdx.x * SB + threadIdx.x;
    red[threadIdx.x] = (i < n) ? cnt[i] : 0;
    __syncthreads();
    for (int off = SB / 2; off > 0; off >>= 1) {
        if (threadIdx.x < off) red[threadIdx.x] += red[threadIdx.x + off];
        __syncthreads();
    }
    if (threadIdx.x == 0) bsum[blockIdx.x] = red[0];
}

// ---- Scan stage 2: each block re-scans bsum (nb<=256) + local scan -> offs, cursor ----
__global__ __launch_bounds__(SB) void scan3_k(const int* __restrict__ cnt,
                                              const int* __restrict__ bsum,
                                              int* __restrict__ offs,
                                              int* __restrict__ cursor, int n, int nb) {
    __shared__ int sb[SB];
    __shared__ int sc[SB];
    int t = threadIdx.x;
    int bv = (t < nb) ? bsum[t] : 0;
    sb[t] = bv;
    __syncthreads();
    for (int off = 1; off < SB; off <<= 1) {
        int u = (t >= off) ? sb[t - off] : 0;
        __syncthreads();
        sb[t] += u;
        __syncthreads();
    }
    int block_off = (blockIdx.x == 0) ? 0 : sb[blockIdx.x - 1];
    __syncthreads();
    int i = blockIdx.x * SB + t;
    int v = (i < n) ? cnt[i] : 0;
    sc[t] = v;
    __syncthreads();
    for (int off = 1; off < SB; off <<= 1) {
        int u = (t >= off) ? sc[t - off] : 0;
        __syncthreads();
        sc[t] += u;
        __syncthreads();
    }
    int excl = sc[t] - v + block_off;
    if (i < n) { offs[i] = excl; cursor[i] = excl; }
    if (i == n - 1) offs[n] = excl + v;
}

// ---- Pass 3: scatter edges into dst-sorted payload (src_bits, w) ----
__global__ __launch_bounds__(256) void reorder_k(const int* __restrict__ ei,
                                                 const float* __restrict__ ew,
                                                 int* __restrict__ cursor,
                                                 float2* __restrict__ se, int n_edges) {
    int e = blockIdx.x * blockDim.x + threadIdx.x;
    if (e >= n_edges) return;
    int s = ei[e];
    int d = ei[n_edges + e];
    int pos = atomicAdd(&cursor[d], 1);
    se[pos] = make_float2(__int_as_float(s), ew[e]);
}

// ---- Per layer: 16-lane-per-node gather (atomic-free) ----
__global__ __launch_bounds__(256) void gather_k(const float4* __restrict__ x4,
                                                const float4* __restrict__ se4,
                                                const int* __restrict__ offs,
                                                float4* __restrict__ agg4, int n_nodes) {
    int t = blockIdx.x * blockDim.x + threadIdx.x;
    int node = t >> 4;
    int li = t & 15;
    if (node >= n_nodes) return;
    int beg = offs[node], end = offs[node + 1];
    const float2* se2 = reinterpret_cast<const float2*>(se4);

    float4 a0 = make_float4(0.f, 0.f, 0.f, 0.f);
    float4 a1 = make_float4(0.f, 0.f, 0.f, 0.f);
    float4 a2 = make_float4(0.f, 0.f, 0.f, 0.f);
    float4 a3 = make_float4(0.f, 0.f, 0.f, 0.f);

    int e = beg;
    if ((e & 1) && e < end) {
        float2 p = se2[e];
        float4 v = x4[(size_t)__float_as_int(p.x) * 16 + li];
        a0.x = fmaf(p.y, v.x, a0.x); a0.y = fmaf(p.y, v.y, a0.y);
        a0.z = fmaf(p.y, v.z, a0.z); a0.w = fmaf(p.y, v.w, a0.w);
        ++e;
    }
    for (; e + 3 < end; e += 4) {
        float4 qa = se4[e >> 1];
        float4 qb = se4[(e >> 1) + 1];
        float4 v0 = x4[(size_t)__float_as_int(qa.x) * 16 + li];
        float4 v1 = x4[(size_t)__float_as_int(qa.z) * 16 + li];
        float4 v2 = x4[(size_t)__float_as_int(qb.x) * 16 + li];
        float4 v3 = x4[(size_t)__float_as_int(qb.z) * 16 + li];
        a0.x = fmaf(qa.y, v0.x, a0.x); a0.y = fmaf(qa.y, v0.y, a0.y);
        a0.z = fmaf(qa.y, v0.z, a0.z); a0.w = fmaf(qa.y, v0.w, a0.w);
        a1.x = fmaf(qa.w, v1.x, a1.x); a1.y = fmaf(qa.w, v1.y, a1.y);
        a1.z = fmaf(qa.w, v1.z, a1.z); a1.w = fmaf(qa.w, v1.w, a1.w);
        a2.x = fmaf(qb.y, v2.x, a2.x); a2.y = fmaf(qb.y, v2.y, a2.y);
        a2.z = fmaf(qb.y, v2.z, a2.z); a2.w = fmaf(qb.y, v2.w, a2.w);
        a3.x = fmaf(qb.w, v3.x, a3.x); a3.y = fmaf(qb.w, v3.y, a3.y);
        a3.z = fmaf(qb.w, v3.z, a3.z); a3.w = fmaf(qb.w, v3.w, a3.w);
    }
    if (e + 1 < end) {
        float4 qa = se4[e >> 1];
        float4 v0 = x4[(size_t)__float_as_int(qa.x) * 16 + li];
        float4 v1 = x4[(size_t)__float_as_int(qa.z) * 16 + li];
        a0.x = fmaf(qa.y, v0.x, a0.x); a0.y = fmaf(qa.y, v0.y, a0.y);
        a0.z = fmaf(qa.y, v0.z, a0.z); a0.w = fmaf(qa.y, v0.w, a0.w);
        a1.x = fmaf(qa.w, v1.x, a1.x); a1.y = fmaf(qa.w, v1.y, a1.y);
        a1.z = fmaf(qa.w, v1.z, a1.z); a1.w = fmaf(qa.w, v1.w, a1.w);
        e += 2;
    }
    if (e < end) {
        float2 p = se2[e];
        float4 v = x4[(size_t)__float_as_int(p.x) * 16 + li];
        a0.x = fmaf(p.y, v.x, a0.x); a0.y = fmaf(p.y, v.y, a0.y);
        a0.z = fmaf(p.y, v.z, a0.z); a0.w = fmaf(p.y, v.w, a0.w);
    }
    float4 r;
    r.x = (a0.x + a1.x) + (a2.x + a3.x);
    r.y = (a0.y + a1.y) + (a2.y + a3.y);
    r.z = (a0.z + a1.z) + (a2.z + a3.z);
    r.w = (a0.w + a1.w) + (a2.w + a3.w);
    agg4[(size_t)node * 16 + li] = r;
}

// ---- MLP: out = relu(agg @ W1.T) @ W2.T, optional row L2-normalize ----
// Quad-per-node: thread q of a node handles j in [q*16, q*16+16); partial o summed
// via shfl_xor butterfly (lanes q^1, q^2); lane q==0 normalizes + writes the row.
// LDS weights padded to stride 17 float4 (rows 16 apart -> distinct banks, no quad conflict).
#define WPAD 17
__device__ __forceinline__ float4 shfl_xor4(float4 v, int m) {
    v.x = __shfl_xor(v.x, m, 64);
    v.y = __shfl_xor(v.y, m, 64);
    v.z = __shfl_xor(v.z, m, 64);
    v.w = __shfl_xor(v.w, m, 64);
    return v;
}

__global__ __launch_bounds__(256) void mlp_k(const float4* __restrict__ agg4,
                                             const float* __restrict__ W1,
                                             const float* __restrict__ W2,
                                             float4* __restrict__ out4,
                                             int n_nodes, int do_norm) {
    __shared__ float4 sW1[DIM * WPAD];    // [j][k4], stride-17 pad
    __shared__ float4 sW2T[DIM * WPAD];   // [j][j2_4] = W2[j2][j] transposed, padded
    for (int i = threadIdx.x; i < DIM * (DIM / 4); i += blockDim.x) {
        int j = i >> 4, k4 = i & 15;
        sW1[j * WPAD + k4] = reinterpret_cast<const float4*>(W1)[i];
    }
    for (int i = threadIdx.x; i < DIM * DIM; i += blockDim.x) {
        int j2 = i >> 6, j = i & 63;   // W2[j2][j]
        reinterpret_cast<float*>(sW2T)[(j * WPAD + (j2 >> 2)) * 4 + (j2 & 3)] = W2[i];
    }
    __syncthreads();

    int t = blockIdx.x * blockDim.x + threadIdx.x;
    int node = t >> 2;
    int q = t & 3;
    if (node >= n_nodes) return;

    float4 a[DIM / 4];
#pragma unroll
    for (int k4 = 0; k4 < DIM / 4; ++k4)
        a[k4] = agg4[(size_t)node * 16 + k4];

    float4 o[DIM / 4];
#pragma unroll
    for (int j4 = 0; j4 < DIM / 4; ++j4) o[j4] = make_float4(0.f, 0.f, 0.f, 0.f);

    int jbase = q << 4;
    for (int jj = 0; jj < 16; ++jj) {
        int j = jbase + jj;
        float h = 0.f;
#pragma unroll
        for (int k4 = 0; k4 < 16; ++k4) {
            float4 wv = sW1[j * WPAD + k4];
            h = fmaf(a[k4].x, wv.x, h);
            h = fmaf(a[k4].y, wv.y, h);
            h = fmaf(a[k4].z, wv.z, h);
            h = fmaf(a[k4].w, wv.w, h);
        }
        h = fmaxf(h, 0.f);
#pragma unroll
        for (int j4 = 0; j4 < 16; ++j4) {
            float4 wv = sW2T[j * WPAD + j4];
            o[j4].x = fmaf(h, wv.x, o[j4].x);
            o[j4].y = fmaf(h, wv.y, o[j4].y);
            o[j4].z = fmaf(h, wv.z, o[j4].z);
            o[j4].w = fmaf(h, wv.w, o[j4].w);
        }
    }

    // sum partials across the quad (lanes node*4 .. node*4+3)
#pragma unroll
    for (int j4 = 0; j4 < 16; ++j4) {
        float4 p = shfl_xor4(o[j4], 1);
        o[j4].x += p.x; o[j4].y += p.y; o[j4].z += p.z; o[j4].w += p.w;
        p = shfl_xor4(o[j4], 2);
        o[j4].x += p.x; o[j4].y += p.y; o[j4].z += p.z; o[j4].w += p.w;
    }

    if (q != 0) return;   // lane 0 of quad holds the full row now

    float scale = 1.f;
    if (do_norm) {
        float ss = 0.f;
#pragma unroll
        for (int j4 = 0; j4 < 16; ++j4) {
            ss = fmaf(o[j4].x, o[j4].x, ss);
            ss = fmaf(o[j4].y, o[j4].y, ss);
            ss = fmaf(o[j4].z, o[j4].z, ss);
            ss = fmaf(o[j4].w, o[j4].w, ss);
        }
        scale = 1.f / fmaxf(sqrtf(ss), 1e-12f);
    }

#pragma unroll
    for (int j4 = 0; j4 < 16; ++j4) {
        float4 v = o[j4];
        v.x *= scale; v.y *= scale; v.z *= scale; v.w *= scale;
        out4[(size_t)node * 16 + j4] = v;
    }
}

extern "C" void kernel_launch(void* const* d_in, const int* in_sizes, int n_in,
                              void* d_out, int out_size, void* d_ws, size_t ws_size,
                              hipStream_t stream) {
    const float* x    = (const float*)d_in[0];
    const int*   ei   = (const int*)d_in[1];     // [2,E]: src row then dst row
    const float* ew   = (const float*)d_in[2];
    const float* W1_0 = (const float*)d_in[3];
    const float* W2_0 = (const float*)d_in[4];
    const float* W1_1 = (const float*)d_in[5];
    const float* W2_1 = (const float*)d_in[6];
    float* out = (float*)d_out;

    int n_nodes = in_sizes[0] / DIM;
    int n_edges = in_sizes[2];

    char* p = (char*)d_ws;
    auto carve = [&](size_t bytes) {
        char* r = p;
        p += (bytes + 15) & ~(size_t)15;
        return r;
    };
    int nb = (n_nodes + SB - 1) / SB;                // 196 scan blocks (<=256)
    int*    cnt    = (int*)carve((size_t)n_nodes * sizeof(int));
    int*    offs   = (int*)carve(((size_t)n_nodes + 1) * sizeof(int));
    int*    cursor = (int*)carve((size_t)n_nodes * sizeof(int));
    int*    bsum   = (int*)carve((size_t)nb * sizeof(int));
    float2* se     = (float2*)carve((size_t)n_edges * sizeof(float2));
    float*  agg    = (float*)carve((size_t)n_nodes * DIM * sizeof(float));

    int eb  = (n_edges + 255) / 256;
    int gb  = (n_nodes * 16 + 255) / 256;    // 16 lanes per node (gather)
    int mb4 = (n_nodes * 4 + 255) / 256;     // 4 threads per node (mlp)

    // ---- build dst-CSR (shared by both layers) ----
    hipMemsetAsync(cnt, 0, (size_t)n_nodes * sizeof(int), stream);
    hist_k<<<eb, 256, 0, stream>>>(ei, cnt, n_edges);
    scan1_k<<<nb, SB, 0, stream>>>(cnt, bsum, n_nodes);
    scan3_k<<<nb, SB, 0, stream>>>(cnt, bsum, offs, cursor, n_nodes, nb);
    reorder_k<<<eb, 256, 0, stream>>>(ei, ew, cursor, se, n_edges);

    // ---- layer 1 ----
    gather_k<<<gb, 256, 0, stream>>>((const float4*)x, (const float4*)se, offs,
                                     (float4*)agg, n_nodes);
    mlp_k<<<mb4, 256, 0, stream>>>((const float4*)agg, W1_0, W2_0,
                                   (float4*)out, n_nodes, 0);

    // ---- layer 2 (x1 lives in d_out) ----
    gather_k<<<gb, 256, 0, stream>>>((const float4*)out, (const float4*)se, offs,
                                     (float4*)agg, n_nodes);
    mlp_k<<<mb4, 256, 0, stream>>>((const float4*)agg, W1_1, W2_1,
                                   (float4*)out, n_nodes, 1);
}

// Round 7
// 293.468 us; speedup vs baseline: 1.2503x; 1.2503x over previous
//
#include <hip/hip_runtime.h>

// WeightedGIN 2-layer + L2-normalize. N=50000, E=800000, D=64.
// dst-CSR built per call (hist + 2-stage scan + reorder), then atomic-free
// 16-lane-per-node gather (float4 rows), quad-per-node MLP (j interleaved
// stride-4 across the quad -> conflict-free stride-17 padded LDS reads).

#define DIM 64
#define SB 256   // scan block size

// ---- Pass 1: histogram of dst ----
__global__ __launch_bounds__(256) void hist_k(const int* __restrict__ ei,
                                              int* __restrict__ cnt, int n_edges) {
    int e = blockIdx.x * blockDim.x + threadIdx.x;
    if (e < n_edges) atomicAdd(&cnt[ei[n_edges + e]], 1);
}

// ---- Scan stage 1: per-block sums of cnt ----
__global__ __launch_bounds__(SB) void scan1_k(const int* __restrict__ cnt,
                                              int* __restrict__ bsum, int n) {
    __shared__ int red[SB];
    int i = blockIdx.x * SB + threadIdx.x;
    red[threadIdx.x] = (i < n) ? cnt[i] : 0;
    __syncthreads();
    for (int off = SB / 2; off > 0; off >>= 1) {
        if (threadIdx.x < off) red[threadIdx.x] += red[threadIdx.x + off];
        __syncthreads();
    }
    if (threadIdx.x == 0) bsum[blockIdx.x] = red[0];
}

// ---- Scan stage 2: each block re-scans bsum (nb<=256) + local scan -> offs, cursor ----
__global__ __launch_bounds__(SB) void scan3_k(const int* __restrict__ cnt,
                                              const int* __restrict__ bsum,
                                              int* __restrict__ offs,
                                              int* __restrict__ cursor, int n, int nb) {
    __shared__ int sb[SB];
    __shared__ int sc[SB];
    int t = threadIdx.x;
    int bv = (t < nb) ? bsum[t] : 0;
    sb[t] = bv;
    __syncthreads();
    for (int off = 1; off < SB; off <<= 1) {
        int u = (t >= off) ? sb[t - off] : 0;
        __syncthreads();
        sb[t] += u;
        __syncthreads();
    }
    int block_off = (blockIdx.x == 0) ? 0 : sb[blockIdx.x - 1];
    __syncthreads();
    int i = blockIdx.x * SB + t;
    int v = (i < n) ? cnt[i] : 0;
    sc[t] = v;
    __syncthreads();
    for (int off = 1; off < SB; off <<= 1) {
        int u = (t >= off) ? sc[t - off] : 0;
        __syncthreads();
        sc[t] += u;
        __syncthreads();
    }
    int excl = sc[t] - v + block_off;
    if (i < n) { offs[i] = excl; cursor[i] = excl; }
    if (i == n - 1) offs[n] = excl + v;
}

// ---- Pass 3: scatter edges into dst-sorted payload (src_bits, w) ----
__global__ __launch_bounds__(256) void reorder_k(const int* __restrict__ ei,
                                                 const float* __restrict__ ew,
                                                 int* __restrict__ cursor,
                                                 float2* __restrict__ se, int n_edges) {
    int e = blockIdx.x * blockDim.x + threadIdx.x;
    if (e >= n_edges) return;
    int s = ei[e];
    int d = ei[n_edges + e];
    int pos = atomicAdd(&cursor[d], 1);
    se[pos] = make_float2(__int_as_float(s), ew[e]);
}

// ---- Per layer: 16-lane-per-node gather (atomic-free) ----
__global__ __launch_bounds__(256) void gather_k(const float4* __restrict__ x4,
                                                const float4* __restrict__ se4,
                                                const int* __restrict__ offs,
                                                float4* __restrict__ agg4, int n_nodes) {
    int t = blockIdx.x * blockDim.x + threadIdx.x;
    int node = t >> 4;
    int li = t & 15;
    if (node >= n_nodes) return;
    int beg = offs[node], end = offs[node + 1];
    const float2* se2 = reinterpret_cast<const float2*>(se4);

    float4 a0 = make_float4(0.f, 0.f, 0.f, 0.f);
    float4 a1 = make_float4(0.f, 0.f, 0.f, 0.f);
    float4 a2 = make_float4(0.f, 0.f, 0.f, 0.f);
    float4 a3 = make_float4(0.f, 0.f, 0.f, 0.f);

    int e = beg;
    if ((e & 1) && e < end) {
        float2 p = se2[e];
        float4 v = x4[(size_t)__float_as_int(p.x) * 16 + li];
        a0.x = fmaf(p.y, v.x, a0.x); a0.y = fmaf(p.y, v.y, a0.y);
        a0.z = fmaf(p.y, v.z, a0.z); a0.w = fmaf(p.y, v.w, a0.w);
        ++e;
    }
    for (; e + 3 < end; e += 4) {
        float4 qa = se4[e >> 1];
        float4 qb = se4[(e >> 1) + 1];
        float4 v0 = x4[(size_t)__float_as_int(qa.x) * 16 + li];
        float4 v1 = x4[(size_t)__float_as_int(qa.z) * 16 + li];
        float4 v2 = x4[(size_t)__float_as_int(qb.x) * 16 + li];
        float4 v3 = x4[(size_t)__float_as_int(qb.z) * 16 + li];
        a0.x = fmaf(qa.y, v0.x, a0.x); a0.y = fmaf(qa.y, v0.y, a0.y);
        a0.z = fmaf(qa.y, v0.z, a0.z); a0.w = fmaf(qa.y, v0.w, a0.w);
        a1.x = fmaf(qa.w, v1.x, a1.x); a1.y = fmaf(qa.w, v1.y, a1.y);
        a1.z = fmaf(qa.w, v1.z, a1.z); a1.w = fmaf(qa.w, v1.w, a1.w);
        a2.x = fmaf(qb.y, v2.x, a2.x); a2.y = fmaf(qb.y, v2.y, a2.y);
        a2.z = fmaf(qb.y, v2.z, a2.z); a2.w = fmaf(qb.y, v2.w, a2.w);
        a3.x = fmaf(qb.w, v3.x, a3.x); a3.y = fmaf(qb.w, v3.y, a3.y);
        a3.z = fmaf(qb.w, v3.z, a3.z); a3.w = fmaf(qb.w, v3.w, a3.w);
    }
    if (e + 1 < end) {
        float4 qa = se4[e >> 1];
        float4 v0 = x4[(size_t)__float_as_int(qa.x) * 16 + li];
        float4 v1 = x4[(size_t)__float_as_int(qa.z) * 16 + li];
        a0.x = fmaf(qa.y, v0.x, a0.x); a0.y = fmaf(qa.y, v0.y, a0.y);
        a0.z = fmaf(qa.y, v0.z, a0.z); a0.w = fmaf(qa.y, v0.w, a0.w);
        a1.x = fmaf(qa.w, v1.x, a1.x); a1.y = fmaf(qa.w, v1.y, a1.y);
        a1.z = fmaf(qa.w, v1.z, a1.z); a1.w = fmaf(qa.w, v1.w, a1.w);
        e += 2;
    }
    if (e < end) {
        float2 p = se2[e];
        float4 v = x4[(size_t)__float_as_int(p.x) * 16 + li];
        a0.x = fmaf(p.y, v.x, a0.x); a0.y = fmaf(p.y, v.y, a0.y);
        a0.z = fmaf(p.y, v.z, a0.z); a0.w = fmaf(p.y, v.w, a0.w);
    }
    float4 r;
    r.x = (a0.x + a1.x) + (a2.x + a3.x);
    r.y = (a0.y + a1.y) + (a2.y + a3.y);
    r.z = (a0.z + a1.z) + (a2.z + a3.z);
    r.w = (a0.w + a1.w) + (a2.w + a3.w);
    agg4[(size_t)node * 16 + li] = r;
}

// ---- MLP: out = relu(agg @ W1.T) @ W2.T, optional row L2-normalize ----
// Quad-per-node. Thread q handles j = q + 4*jj (jj=0..15): quad members read
// CONSECUTIVE padded rows (stride 17 float4 => bank distance 4) -> the quad's four
// ds_read_b128 hit bank groups {0-3,4-7,8-11,12-15}: conflict-free; lanes sharing q
// broadcast. Partial o summed via shfl_xor butterfly; lane q==0 normalizes+writes.
#define WPAD 17
__device__ __forceinline__ float4 shfl_xor4(float4 v, int m) {
    v.x = __shfl_xor(v.x, m, 64);
    v.y = __shfl_xor(v.y, m, 64);
    v.z = __shfl_xor(v.z, m, 64);
    v.w = __shfl_xor(v.w, m, 64);
    return v;
}

__global__ __launch_bounds__(256) void mlp_k(const float4* __restrict__ agg4,
                                             const float* __restrict__ W1,
                                             const float* __restrict__ W2,
                                             float4* __restrict__ out4,
                                             int n_nodes, int do_norm) {
    __shared__ float4 sW1[DIM * WPAD];    // [j][k4], stride-17 pad
    __shared__ float4 sW2T[DIM * WPAD];   // [j][j2_4] = W2[j2][j] transposed, padded
    for (int i = threadIdx.x; i < DIM * (DIM / 4); i += blockDim.x) {
        int j = i >> 4, k4 = i & 15;
        sW1[j * WPAD + k4] = reinterpret_cast<const float4*>(W1)[i];
    }
    for (int i = threadIdx.x; i < DIM * DIM; i += blockDim.x) {
        int j2 = i >> 6, j = i & 63;   // W2[j2][j]
        reinterpret_cast<float*>(sW2T)[(j * WPAD + (j2 >> 2)) * 4 + (j2 & 3)] = W2[i];
    }
    __syncthreads();

    int t = blockIdx.x * blockDim.x + threadIdx.x;
    int node = t >> 2;
    int q = t & 3;
    if (node >= n_nodes) return;

    float4 a[DIM / 4];
#pragma unroll
    for (int k4 = 0; k4 < DIM / 4; ++k4)
        a[k4] = agg4[(size_t)node * 16 + k4];

    float4 o[DIM / 4];
#pragma unroll
    for (int j4 = 0; j4 < DIM / 4; ++j4) o[j4] = make_float4(0.f, 0.f, 0.f, 0.f);

    for (int jj = 0; jj < 16; ++jj) {
        int j = q + (jj << 2);          // stride-4 interleave across the quad
        float h = 0.f;
#pragma unroll
        for (int k4 = 0; k4 < 16; ++k4) {
            float4 wv = sW1[j * WPAD + k4];
            h = fmaf(a[k4].x, wv.x, h);
            h = fmaf(a[k4].y, wv.y, h);
            h = fmaf(a[k4].z, wv.z, h);
            h = fmaf(a[k4].w, wv.w, h);
        }
        h = fmaxf(h, 0.f);
#pragma unroll
        for (int j4 = 0; j4 < 16; ++j4) {
            float4 wv = sW2T[j * WPAD + j4];
            o[j4].x = fmaf(h, wv.x, o[j4].x);
            o[j4].y = fmaf(h, wv.y, o[j4].y);
            o[j4].z = fmaf(h, wv.z, o[j4].z);
            o[j4].w = fmaf(h, wv.w, o[j4].w);
        }
    }

    // sum partials across the quad (lanes node*4 .. node*4+3)
#pragma unroll
    for (int j4 = 0; j4 < 16; ++j4) {
        float4 p = shfl_xor4(o[j4], 1);
        o[j4].x += p.x; o[j4].y += p.y; o[j4].z += p.z; o[j4].w += p.w;
        p = shfl_xor4(o[j4], 2);
        o[j4].x += p.x; o[j4].y += p.y; o[j4].z += p.z; o[j4].w += p.w;
    }

    if (q != 0) return;   // lane 0 of quad holds the full row now

    float scale = 1.f;
    if (do_norm) {
        float ss = 0.f;
#pragma unroll
        for (int j4 = 0; j4 < 16; ++j4) {
            ss = fmaf(o[j4].x, o[j4].x, ss);
            ss = fmaf(o[j4].y, o[j4].y, ss);
            ss = fmaf(o[j4].z, o[j4].z, ss);
            ss = fmaf(o[j4].w, o[j4].w, ss);
        }
        scale = 1.f / fmaxf(sqrtf(ss), 1e-12f);
    }

#pragma unroll
    for (int j4 = 0; j4 < 16; ++j4) {
        float4 v = o[j4];
        v.x *= scale; v.y *= scale; v.z *= scale; v.w *= scale;
        out4[(size_t)node * 16 + j4] = v;
    }
}

extern "C" void kernel_launch(void* const* d_in, const int* in_sizes, int n_in,
                              void* d_out, int out_size, void* d_ws, size_t ws_size,
                              hipStream_t stream) {
    const float* x    = (const float*)d_in[0];
    const int*   ei   = (const int*)d_in[1];     // [2,E]: src row then dst row
    const float* ew   = (const float*)d_in[2];
    const float* W1_0 = (const float*)d_in[3];
    const float* W2_0 = (const float*)d_in[4];
    const float* W1_1 = (const float*)d_in[5];
    const float* W2_1 = (const float*)d_in[6];
    float* out = (float*)d_out;

    int n_nodes = in_sizes[0] / DIM;
    int n_edges = in_sizes[2];

    char* p = (char*)d_ws;
    auto carve = [&](size_t bytes) {
        char* r = p;
        p += (bytes + 15) & ~(size_t)15;
        return r;
    };
    int nb = (n_nodes + SB - 1) / SB;                // 196 scan blocks (<=256)
    int*    cnt    = (int*)carve((size_t)n_nodes * sizeof(int));
    int*    offs   = (int*)carve(((size_t)n_nodes + 1) * sizeof(int));
    int*    cursor = (int*)carve((size_t)n_nodes * sizeof(int));
    int*    bsum   = (int*)carve((size_t)nb * sizeof(int));
    float2* se     = (float2*)carve((size_t)n_edges * sizeof(float2));
    float*  agg    = (float*)carve((size_t)n_nodes * DIM * sizeof(float));

    int eb  = (n_edges + 255) / 256;
    int gb  = (n_nodes * 16 + 255) / 256;    // 16 lanes per node (gather)
    int mb4 = (n_nodes * 4 + 255) / 256;     // 4 threads per node (mlp)

    // ---- build dst-CSR (shared by both layers) ----
    hipMemsetAsync(cnt, 0, (size_t)n_nodes * sizeof(int), stream);
    hist_k<<<eb, 256, 0, stream>>>(ei, cnt, n_edges);
    scan1_k<<<nb, SB, 0, stream>>>(cnt, bsum, n_nodes);
    scan3_k<<<nb, SB, 0, stream>>>(cnt, bsum, offs, cursor, n_nodes, nb);
    reorder_k<<<eb, 256, 0, stream>>>(ei, ew, cursor, se, n_edges);

    // ---- layer 1 ----
    gather_k<<<gb, 256, 0, stream>>>((const float4*)x, (const float4*)se, offs,
                                     (float4*)agg, n_nodes);
    mlp_k<<<mb4, 256, 0, stream>>>((const float4*)agg, W1_0, W2_0,
                                   (float4*)out, n_nodes, 0);

    // ---- layer 2 (x1 lives in d_out) ----
    gather_k<<<gb, 256, 0, stream>>>((const float4*)out, (const float4*)se, offs,
                                     (float4*)agg, n_nodes);
    mlp_k<<<mb4, 256, 0, stream>>>((const float4*)agg, W1_1, W2_1,
                                   (float4*)out, n_nodes, 1);
}